// Round 25
// baseline (50.602 us; speedup 1.0000x reference)
//
#include <hip/hip_runtime.h>
#include <hip/hip_bf16.h>

typedef unsigned int uint;
typedef unsigned short ushort;

// Dims
#define Bn 16
#define Dd 256
#define Nn 4096
#define Hh 4
#define Kk 16
#define Vv 64
#define Rr 23
#define Cc 144   // 64 q + 16 k + 64 v
#define NRT 9    // 144/16 row-tiles

typedef short bf16x8s __attribute__((ext_vector_type(8)));
typedef float f32x4 __attribute__((ext_vector_type(4)));
typedef float f32x8 __attribute__((ext_vector_type(8)));

static __device__ __forceinline__ ushort f2bf(float f) {
    __hip_bfloat16 h = __float2bfloat16(f);
    return __builtin_bit_cast(ushort, h);
}
static __device__ __forceinline__ float bf2f(ushort u) {
    return __uint_as_float(((uint)u) << 16);
}
static __device__ __forceinline__ float bflo(uint u) { return __uint_as_float(u << 16); }
static __device__ __forceinline__ float bfhi(uint u) { return __uint_as_float(u & 0xffff0000u); }

// ---------------- Kernel 1: pack weights + cw fragments + zero num/den ----------------
__global__ __launch_bounds__(256) void pack_kernel(
    const float* __restrict__ Wq, const float* __restrict__ qg, const float* __restrict__ qb,
    const float* __restrict__ qm, const float* __restrict__ qv,
    const float* __restrict__ Wk, const float* __restrict__ Wv,
    const float* __restrict__ vg, const float* __restrict__ vb,
    const float* __restrict__ vm, const float* __restrict__ vvar,
    const float* __restrict__ conv_w,
    ushort* __restrict__ Wf16, float* __restrict__ bias,
    ushort* __restrict__ cwf, float* __restrict__ num, float* __restrict__ den) {
    int c = blockIdx.x;       // 0..143
    int t = threadIdx.x;      // 0..255
    int d = t;
    float scale, bs;
    const float* src;
    if (c < 64) {
        scale = qg[c] * rsqrtf(qv[c] + 1e-5f);
        bs = qb[c] - qm[c] * scale;
        src = Wq + c * Dd;
    } else if (c < 80) {
        scale = 1.f; bs = 0.f;
        src = Wk + (c - 64) * Dd;
    } else {
        int j = c - 80;
        scale = vg[j] * rsqrtf(vvar[j] + 1e-5f);
        bs = vb[j] - vm[j] * scale;
        src = Wv + j * Dd;
    }
    int rt = c >> 4, lm = c & 15;
    int kk = d >> 5, hi = (d >> 3) & 3, j = d & 7;
    Wf16[((rt * 8 + kk) * 64 + hi * 16 + lm) * 8 + j] = f2bf(src[d] * scale);
    if (d == 0) bias[c] = bs;

    // block 0: cw^T A-fragments, tile stride 512 (64 lanes x 8 elems)
    if (c == 0) {
#pragma unroll
        for (int m = 0; m < 4; m++) {
            int flat = t + 256 * m;           // 0..1023
            int mt = flat >> 9, rem = flat & 511;
            int l = rem >> 3, jj = rem & 7;
            int r = mt * 16 + (l & 15);
            int k = (l >> 4) * 8 + jj;
            float v = (r < Rr && k < Kk) ? conv_w[k * Rr + r] : 0.f;
            cwf[flat] = f2bf(v);
        }
    }
    // block 1: zero num (16384 f) and den (256 f)
    if (c == 1) {
        float4 z = {0.f, 0.f, 0.f, 0.f};
#pragma unroll
        for (int m = 0; m < 16; m++)
            reinterpret_cast<float4*>(num)[t + 256 * m] = z;
        if (t < 64) reinterpret_cast<float4*>(den)[t] = z;
    }
}

// ---------------- Kernel 2: MFMA projection + fused exp/lam contraction (R24) ---------
__global__ __launch_bounds__(256, 4) void proj_mfma_kernel(
    const float* __restrict__ x, const ushort* __restrict__ Wf16,
    const float* __restrict__ bias,
    ushort* __restrict__ qbufT, ushort* __restrict__ vbufT,
    float* __restrict__ num, float* __restrict__ den) {
    __shared__ ushort Wlds[NRT * 2 * 64 * 8];   // 18432 B (2 k-steps per phase)

    int b = blockIdx.y;
    int n0 = blockIdx.x * 64;
    int t = threadIdx.x;
    int w = t >> 6, l = t & 63;
    int lm = l & 15, hi = l >> 4;
    int n = n0 + w * 16 + lm;     // this lane's output column

    const uint* WfU = (const uint*)Wf16;
    uint* WldsU = (uint*)Wlds;

    f32x4 acc[NRT];
#pragma unroll
    for (int rt = 0; rt < NRT; rt++) acc[rt] = (f32x4){0.f, 0.f, 0.f, 0.f};

    const float* xb = x + (size_t)b * Dd * Nn + n;

    auto load8 = [&](int kk) -> f32x8 {
        const float* xp = xb + (size_t)(kk * 32 + hi * 8) * Nn;
        f32x8 r;
        r[0] = xp[0];
        r[1] = xp[(size_t)1 * Nn];
        r[2] = xp[(size_t)2 * Nn];
        r[3] = xp[(size_t)3 * Nn];
        r[4] = xp[(size_t)4 * Nn];
        r[5] = xp[(size_t)5 * Nn];
        r[6] = xp[(size_t)6 * Nn];
        r[7] = xp[(size_t)7 * Nn];
        return r;
    };
    auto cvt8 = [&](f32x8 f) -> bf16x8s {
        bf16x8s o;
#pragma unroll
        for (int j = 0; j < 8; j++) o[j] = (short)f2bf(f[j]);
        return o;
    };

    f32x8 xc0 = load8(0), xc1 = load8(1);
    f32x8 xn0 = xc0, xn1 = xc1;

#pragma unroll
    for (int p = 0; p < 4; p++) {
        int kb = p * 2;
        if (p) __syncthreads();
#pragma unroll
        for (int i = 0; i < 18; i++) {
            int flat = t + 256 * i;
            int f2 = flat >> 8;          // rt*2 + kkl
            int rt = f2 >> 1, kkl = f2 & 1;
            WldsU[flat] = WfU[((rt * 8 + kb + kkl) << 8) + (flat & 255)];
        }
        __syncthreads();

        bf16x8s bf0 = cvt8(xc0);
        bf16x8s bf1 = cvt8(xc1);
        if (p < 3) {                     // prefetch next phase during MFMAs
            xn0 = load8(kb + 2);
            xn1 = load8(kb + 3);
        }
#pragma unroll
        for (int rt = 0; rt < NRT; rt++) {
            bf16x8s afrag = *reinterpret_cast<const bf16x8s*>(
                &Wlds[(size_t)((rt * 2 + 0) * 64 + l) * 8]);
            acc[rt] = __builtin_amdgcn_mfma_f32_16x16x32_bf16(afrag, bf0, acc[rt], 0, 0, 0);
        }
#pragma unroll
        for (int rt = 0; rt < NRT; rt++) {
            bf16x8s afrag = *reinterpret_cast<const bf16x8s*>(
                &Wlds[(size_t)((rt * 2 + 1) * 64 + l) * 8]);
            acc[rt] = __builtin_amdgcn_mfma_f32_16x16x32_bf16(afrag, bf1, acc[rt], 0, 0, 0);
        }
        xc0 = xn0;
        xc1 = xn1;
    }

    __syncthreads();   // done reading Wlds; reuse as transpose buffer
    {
        int nl = w * 16 + lm;
#pragma unroll
        for (int rt = 0; rt < 4; rt++)
#pragma unroll
            for (int rr = 0; rr < 4; rr++) {
                int kq = hi * 4 + rr;
                Wlds[nl * 72 + kq * 4 + rt] = f2bf(acc[rt][rr] + bias[rt * 16 + kq]);
            }
#pragma unroll
        for (int rt = 5; rt < 9; rt++)
#pragma unroll
            for (int rr = 0; rr < 4; rr++) {
                int v = (rt - 5) * 16 + hi * 4 + rr;
                Wlds[4608 + nl * 72 + v] = f2bf(acc[rt][rr] + bias[80 + v]);
            }
    }
    __syncthreads();

#pragma unroll
    for (int m = 0; m < 2; m++) {
        int i = t + 256 * m;
        int row = i >> 3, seg = i & 7;
        uint4 u = *reinterpret_cast<const uint4*>(&Wlds[row * 72 + seg * 8]);
        *reinterpret_cast<uint4*>(&qbufT[((size_t)b * Nn + n0 + row) * 64 + seg * 8]) = u;
    }
#pragma unroll
    for (int m = 0; m < 2; m++) {
        int i = t + 256 * m;
        int row = i >> 3, seg = i & 7;
        uint4 u = *reinterpret_cast<const uint4*>(&Wlds[4608 + row * 72 + seg * 8]);
        *reinterpret_cast<uint4*>(&vbufT[((size_t)b * Nn + n0 + row) * 64 + seg * 8]) = u;
    }

    // ---- fused exp + lam contraction ----
    float ev[4];
#pragma unroll
    for (int rr = 0; rr < 4; rr++)
        ev[rr] = __expf(acc[4][rr] + bias[64 + hi * 4 + rr]);
    __syncthreads();
    float* eks = reinterpret_cast<float*>(Wlds);   // eks[k][n]: 16x64 fp32 (q region)
    {
        int nl = w * 16 + lm;
#pragma unroll
        for (int rr = 0; rr < 4; rr++)
            eks[(hi * 4 + rr) * 64 + nl] = ev[rr];
    }
    __syncthreads();
    {
        int v = t & 63, k0 = t >> 6;
        float a4[4] = {0.f, 0.f, 0.f, 0.f};
        for (int nl = 0; nl < 64; nl++) {
            float wv = bf2f(Wlds[4608 + nl * 72 + v]);
#pragma unroll
            for (int j2 = 0; j2 < 4; j2++)
                a4[j2] += eks[(k0 + 4 * j2) * 64 + nl] * wv;
        }
#pragma unroll
        for (int j2 = 0; j2 < 4; j2++)
            atomicAdd(&num[((size_t)b * Kk + k0 + 4 * j2) * Vv + v], a4[j2]);
        if (t < Kk) {
            float s = 0.f;
#pragma unroll
            for (int nl = 0; nl < 64; nl++) s += eks[t * 64 + nl];
            atomicAdd(&den[(size_t)b * Kk + t], s);
        }
    }
}

// ---------------- Kernel 3: fused output via MFMA, TN=16 / K=64 ----------------
// A(64x64): cols 0..37 vv window (n0-11..n0+26), cols 38..53 lc, 54..63 zero.
// S_h(64x16): rows m=nl+r (band, m<=37), rows 38+k = q[k][h], 54..63 zero.
// Per wave: 2 G-MFMAs (cw^T x Q_h) + 8 main MFMAs. LDS 20 KB -> 8 blocks/CU.
#define TN 16
__global__ __launch_bounds__(256, 4) void fused_out_kernel(
    const ushort* __restrict__ qbufT, const ushort* __restrict__ vbufT,
    const ushort* __restrict__ cwf, const float* __restrict__ num,
    const float* __restrict__ den, const float* __restrict__ conv_b,
    float* __restrict__ out) {
    __shared__ ushort Af[8 * 64 * 8];       // 8192 B
    __shared__ ushort Sf[4][8 * 16 * 8];    // 8192 B
    __shared__ ushort Qf[4][64 * 8];        // 4096 B

    int b = blockIdx.y;
    int n0 = blockIdx.x * TN;
    int t = threadIdx.x;
    int l = t & 63;

    // ---- issue all global loads first ----
    // vv: 38 rows x 8 uint4 = 304
    uint4 vld0 = {0, 0, 0, 0}, vld1 = {0, 0, 0, 0};
    {
        int j = t >> 3, seg = t & 7;
        int n = n0 - 11 + j;
        if (n >= 0 && n < Nn)
            vld0 = *reinterpret_cast<const uint4*>(&vbufT[((size_t)b * Nn + n) * 64 + seg * 8]);
        int i2 = t + 256;
        if (i2 < 304) {
            int j2 = i2 >> 3, seg2 = i2 & 7;
            int n2 = n0 - 11 + j2;
            if (n2 >= 0 && n2 < Nn)
                vld1 = *reinterpret_cast<const uint4*>(&vbufT[((size_t)b * Nn + n2) * 64 + seg2 * 8]);
        }
    }
    // q: 16 nl x 16 uint2 = 256 (one per thread); k = t&15, nl = t>>4
    uint2 qld;
    {
        int nl = t >> 4, k = t & 15;
        qld = *reinterpret_cast<const uint2*>(
            &qbufT[((size_t)b * Nn + n0 + nl) * 64 + k * 4]);
    }
    uint4 cwld0 = *reinterpret_cast<const uint4*>(&cwf[(0 * 64 + l) * 8]);
    uint4 cwld1 = *reinterpret_cast<const uint4*>(&cwf[(1 * 64 + l) * 8]);
    float4 lcl = *reinterpret_cast<const float4*>(&num[(size_t)b * Kk * Vv + t * 4]);
    float dk = den[(size_t)b * Kk + (t >> 4)];
    float cb = conv_b[t >> 4];

    // ---- zero-init all fragments ----
    uint4 z4 = {0, 0, 0, 0};
    reinterpret_cast<uint4*>(Af)[t]       = z4;
    reinterpret_cast<uint4*>(Af)[t + 256] = z4;
    reinterpret_cast<uint4*>(Sf)[t]       = z4;
    reinterpret_cast<uint4*>(Sf)[t + 256] = z4;
    reinterpret_cast<uint4*>(Qf)[t]       = z4;
    __syncthreads();

    // ---- scatter fills ----
    // vv -> A cols 0..37 (col c, elem j=c&7, tile c>>3; lane = v)
    {
        int c = t >> 3, seg = t & 7;
        ushort* base = &Af[((c >> 3) * 64 + seg * 8) * 8 + (c & 7)];
        uint va[4] = {vld0.x, vld0.y, vld0.z, vld0.w};
#pragma unroll
        for (int e = 0; e < 4; e++) {
            base[(2 * e + 0) * 8] = (ushort)(va[e] & 0xffff);
            base[(2 * e + 1) * 8] = (ushort)(va[e] >> 16);
        }
        int i2 = t + 256;
        if (i2 < 304) {
            int c2 = i2 >> 3, seg2 = i2 & 7;
            ushort* base2 = &Af[((c2 >> 3) * 64 + seg2 * 8) * 8 + (c2 & 7)];
            uint vb4[4] = {vld1.x, vld1.y, vld1.z, vld1.w};
#pragma unroll
            for (int e = 0; e < 4; e++) {
                base2[(2 * e + 0) * 8] = (ushort)(vb4[e] & 0xffff);
                base2[(2 * e + 1) * 8] = (ushort)(vb4[e] >> 16);
            }
        }
    }
    // lc = num/den + cb -> A cols 38..53
    {
        int k = t >> 4, v0 = (t & 15) * 4;
        int c = 38 + k;
        ushort* base = &Af[((c >> 3) * 64 + v0) * 8 + (c & 7)];
        float inv = 1.f / dk;
        base[0]  = f2bf(lcl.x * inv + cb);
        base[8]  = f2bf(lcl.y * inv + cb);
        base[16] = f2bf(lcl.z * inv + cb);
        base[24] = f2bf(lcl.w * inv + cb);
    }
    // q -> S rows 38..53 AND Qf B-fragments (k = t&15, nl = t>>4)
    {
        int nl = t >> 4, k = t & 15;
        int m = 38 + k;
        int off = ((m >> 3) * 16 + nl) * 8 + (m & 7);
        Sf[0][off] = (ushort)(qld.x & 0xffff);
        Sf[1][off] = (ushort)(qld.x >> 16);
        Sf[2][off] = (ushort)(qld.y & 0xffff);
        Sf[3][off] = (ushort)(qld.y >> 16);
        int qoff = ((k >> 3) * 16 + nl) * 8 + (k & 7);
        Qf[0][qoff] = (ushort)(qld.x & 0xffff);
        Qf[1][qoff] = (ushort)(qld.x >> 16);
        Qf[2][qoff] = (ushort)(qld.y & 0xffff);
        Qf[3][qoff] = (ushort)(qld.y >> 16);
    }
    __syncthreads();

    // ---- G-MFMA: wave h computes G_h(23x16) = cw^T x Q_h, scatters into Sf band ----
    int h = t >> 6;
    int lm = l & 15, hif = l >> 4;
    {
        bf16x8s cwfr0 = __builtin_bit_cast(bf16x8s, cwld0);
        bf16x8s cwfr1 = __builtin_bit_cast(bf16x8s, cwld1);
        bf16x8s qfr = *reinterpret_cast<const bf16x8s*>(&Qf[h][l * 8]);
        f32x4 g0 = __builtin_amdgcn_mfma_f32_16x16x32_bf16(
            cwfr0, qfr, (f32x4){0.f, 0.f, 0.f, 0.f}, 0, 0, 0);
        f32x4 g1 = __builtin_amdgcn_mfma_f32_16x16x32_bf16(
            cwfr1, qfr, (f32x4){0.f, 0.f, 0.f, 0.f}, 0, 0, 0);
        // scatter: r = mt*16 + hif*4 + rr (r<23), m = lm + r
#pragma unroll
        for (int rr = 0; rr < 4; rr++) {
            int r = hif * 4 + rr;          // mt=0: r 0..15 always < 23
            int m = lm + r;
            Sf[h][((m >> 3) * 16 + lm) * 8 + (m & 7)] = f2bf(g0[rr]);
        }
#pragma unroll
        for (int rr = 0; rr < 4; rr++) {
            int r = 16 + hif * 4 + rr;     // mt=1: r 16..31, keep r<23
            if (r < Rr) {
                int m = lm + r;
                Sf[h][((m >> 3) * 16 + lm) * 8 + (m & 7)] = f2bf(g1[rr]);
            }
        }
    }
    __syncthreads();

    // ---- main MFMA: wave = h; 2 k-tiles x 4 m-tiles ----
    f32x4 acc[4];
#pragma unroll
    for (int mt = 0; mt < 4; mt++) acc[mt] = (f32x4){0.f, 0.f, 0.f, 0.f};

#pragma unroll
    for (int kk = 0; kk < 2; kk++) {
        bf16x8s bfr = *reinterpret_cast<const bf16x8s*>(
            &Sf[h][((kk * 4 + hif) * 16 + lm) * 8]);
#pragma unroll
        for (int mt = 0; mt < 4; mt++) {
            bf16x8s afr = *reinterpret_cast<const bf16x8s*>(
                &Af[((kk * 4 + hif) * 64 + mt * 16 + lm) * 8]);
            acc[mt] = __builtin_amdgcn_mfma_f32_16x16x32_bf16(afr, bfr, acc[mt], 0, 0, 0);
        }
    }

    // ---- store: C layout col=lane&15 (n), row=(lane>>4)*4+reg (v) ----
    float* ob = out + ((size_t)b * 256 + h * 64) * Nn + n0;
#pragma unroll
    for (int mt = 0; mt < 4; mt++)
#pragma unroll
        for (int rr = 0; rr < 4; rr++) {
            int v = mt * 16 + hif * 4 + rr;
            ob[(size_t)v * Nn + lm] = acc[mt][rr];
        }
}

extern "C" void kernel_launch(void* const* d_in, const int* in_sizes, int n_in,
                              void* d_out, int out_size, void* d_ws, size_t ws_size,
                              hipStream_t stream) {
    const float* x      = (const float*)d_in[0];
    const float* Wq     = (const float*)d_in[1];
    const float* qg     = (const float*)d_in[2];
    const float* qb     = (const float*)d_in[3];
    const float* qm     = (const float*)d_in[4];
    const float* qv     = (const float*)d_in[5];
    const float* Wk     = (const float*)d_in[6];
    const float* Wv     = (const float*)d_in[7];
    const float* vg     = (const float*)d_in[8];
    const float* vb     = (const float*)d_in[9];
    const float* vm     = (const float*)d_in[10];
    const float* vvar   = (const float*)d_in[11];
    const float* conv_w = (const float*)d_in[12];
    const float* conv_b = (const float*)d_in[13];
    float* out = (float*)d_out;

    float* wsf = (float*)d_ws;
    ushort* Wf16  = (ushort*)wsf;                       // 36864 u16 = 18432 f
    float*  bias  = wsf + 18432;                        // 256 f
    float*  num   = wsf + 18688;                        // 16384 f
    float*  den   = wsf + 35072;                        // 256 f
    ushort* cwf   = (ushort*)(wsf + 35328);             // 1024 u16 = 512 f
    ushort* qbufT = (ushort*)(wsf + 35840);             // 16*4096*64 u16 = 2097152 f
    ushort* vbufT = (ushort*)(wsf + 2132992);           // 16*4096*64 u16

    pack_kernel<<<Cc, 256, 0, stream>>>(Wq, qg, qb, qm, qv, Wk, Wv, vg, vb, vm, vvar,
                                        conv_w, Wf16, bias, cwf, num, den);
    proj_mfma_kernel<<<dim3(Nn / 64, Bn), 256, 0, stream>>>(x, Wf16, bias,
                                                            qbufT, vbufT, num, den);
    fused_out_kernel<<<dim3(Nn / TN, Bn), 256, 0, stream>>>(qbufT, vbufT, cwf, num, den,
                                                            conv_b, out);
}

// Round 26
// 47.360 us; speedup vs baseline: 1.0685x; 1.0685x over previous
//
#include <hip/hip_runtime.h>
#include <hip/hip_bf16.h>

typedef unsigned int uint;
typedef unsigned short ushort;

// Dims
#define Bn 16
#define Dd 256
#define Nn 4096
#define Hh 4
#define Kk 16
#define Vv 64
#define Rr 23
#define Cc 144   // 64 q + 16 k + 64 v
#define NRT 9    // 144/16 row-tiles

typedef short bf16x8s __attribute__((ext_vector_type(8)));
typedef float f32x4 __attribute__((ext_vector_type(4)));
typedef float f32x8 __attribute__((ext_vector_type(8)));

static __device__ __forceinline__ ushort f2bf(float f) {
    __hip_bfloat16 h = __float2bfloat16(f);
    return __builtin_bit_cast(ushort, h);
}
static __device__ __forceinline__ float bf2f(ushort u) {
    return __uint_as_float(((uint)u) << 16);
}
static __device__ __forceinline__ float bflo(uint u) { return __uint_as_float(u << 16); }
static __device__ __forceinline__ float bfhi(uint u) { return __uint_as_float(u & 0xffff0000u); }

// ---------------- Kernel 1: pack weights + cw fragments + zero num/den ----------------
__global__ __launch_bounds__(256) void pack_kernel(
    const float* __restrict__ Wq, const float* __restrict__ qg, const float* __restrict__ qb,
    const float* __restrict__ qm, const float* __restrict__ qv,
    const float* __restrict__ Wk, const float* __restrict__ Wv,
    const float* __restrict__ vg, const float* __restrict__ vb,
    const float* __restrict__ vm, const float* __restrict__ vvar,
    const float* __restrict__ conv_w,
    ushort* __restrict__ Wf16, float* __restrict__ bias,
    ushort* __restrict__ cwf, float* __restrict__ num, float* __restrict__ den) {
    int c = blockIdx.x;       // 0..143
    int t = threadIdx.x;      // 0..255
    int d = t;
    float scale, bs;
    const float* src;
    if (c < 64) {
        scale = qg[c] * rsqrtf(qv[c] + 1e-5f);
        bs = qb[c] - qm[c] * scale;
        src = Wq + c * Dd;
    } else if (c < 80) {
        scale = 1.f; bs = 0.f;
        src = Wk + (c - 64) * Dd;
    } else {
        int j = c - 80;
        scale = vg[j] * rsqrtf(vvar[j] + 1e-5f);
        bs = vb[j] - vm[j] * scale;
        src = Wv + j * Dd;
    }
    int rt = c >> 4, lm = c & 15;
    int kk = d >> 5, hi = (d >> 3) & 3, j = d & 7;
    Wf16[((rt * 8 + kk) * 64 + hi * 16 + lm) * 8 + j] = f2bf(src[d] * scale);
    if (d == 0) bias[c] = bs;

    // block 0: cw^T A-fragments, tile stride 512 (64 lanes x 8 elems)
    if (c == 0) {
#pragma unroll
        for (int m = 0; m < 4; m++) {
            int flat = t + 256 * m;           // 0..1023
            int mt = flat >> 9, rem = flat & 511;
            int l = rem >> 3, jj = rem & 7;
            int r = mt * 16 + (l & 15);
            int k = (l >> 4) * 8 + jj;
            float v = (r < Rr && k < Kk) ? conv_w[k * Rr + r] : 0.f;
            cwf[flat] = f2bf(v);
        }
    }
    // block 1: zero num (16384 f) and den (256 f)
    if (c == 1) {
        float4 z = {0.f, 0.f, 0.f, 0.f};
#pragma unroll
        for (int m = 0; m < 16; m++)
            reinterpret_cast<float4*>(num)[t + 256 * m] = z;
        if (t < 64) reinterpret_cast<float4*>(den)[t] = z;
    }
}

// ---------------- Kernel 2: MFMA projection + fused exp/lam contraction ----------------
// x loads register-double-buffered across phases (f32x8 named vectors): next phase's 16
// values issue during current phase's MFMAs, drain at the next barrier -> latency hidden.
__global__ __launch_bounds__(256, 4) void proj_mfma_kernel(
    const float* __restrict__ x, const ushort* __restrict__ Wf16,
    const float* __restrict__ bias,
    ushort* __restrict__ qbufT, ushort* __restrict__ vbufT,
    float* __restrict__ num, float* __restrict__ den) {
    __shared__ ushort Wlds[NRT * 2 * 64 * 8];   // 18432 B (2 k-steps per phase)

    int b = blockIdx.y;
    int n0 = blockIdx.x * 64;
    int t = threadIdx.x;
    int w = t >> 6, l = t & 63;
    int lm = l & 15, hi = l >> 4;
    int n = n0 + w * 16 + lm;     // this lane's output column

    const uint* WfU = (const uint*)Wf16;
    uint* WldsU = (uint*)Wlds;

    f32x4 acc[NRT];
#pragma unroll
    for (int rt = 0; rt < NRT; rt++) acc[rt] = (f32x4){0.f, 0.f, 0.f, 0.f};

    const float* xb = x + (size_t)b * Dd * Nn + n;

    auto load8 = [&](int kk) -> f32x8 {
        const float* xp = xb + (size_t)(kk * 32 + hi * 8) * Nn;
        f32x8 r;
        r[0] = xp[0];
        r[1] = xp[(size_t)1 * Nn];
        r[2] = xp[(size_t)2 * Nn];
        r[3] = xp[(size_t)3 * Nn];
        r[4] = xp[(size_t)4 * Nn];
        r[5] = xp[(size_t)5 * Nn];
        r[6] = xp[(size_t)6 * Nn];
        r[7] = xp[(size_t)7 * Nn];
        return r;
    };
    auto cvt8 = [&](f32x8 f) -> bf16x8s {
        bf16x8s o;
#pragma unroll
        for (int j = 0; j < 8; j++) o[j] = (short)f2bf(f[j]);
        return o;
    };

    f32x8 xc0 = load8(0), xc1 = load8(1);
    f32x8 xn0 = xc0, xn1 = xc1;

#pragma unroll
    for (int p = 0; p < 4; p++) {
        int kb = p * 2;
        if (p) __syncthreads();
#pragma unroll
        for (int i = 0; i < 18; i++) {
            int flat = t + 256 * i;
            int f2 = flat >> 8;          // rt*2 + kkl
            int rt = f2 >> 1, kkl = f2 & 1;
            WldsU[flat] = WfU[((rt * 8 + kb + kkl) << 8) + (flat & 255)];
        }
        __syncthreads();

        bf16x8s bf0 = cvt8(xc0);
        bf16x8s bf1 = cvt8(xc1);
        if (p < 3) {                     // prefetch next phase during MFMAs
            xn0 = load8(kb + 2);
            xn1 = load8(kb + 3);
        }
#pragma unroll
        for (int rt = 0; rt < NRT; rt++) {
            bf16x8s afrag = *reinterpret_cast<const bf16x8s*>(
                &Wlds[(size_t)((rt * 2 + 0) * 64 + l) * 8]);
            acc[rt] = __builtin_amdgcn_mfma_f32_16x16x32_bf16(afrag, bf0, acc[rt], 0, 0, 0);
        }
#pragma unroll
        for (int rt = 0; rt < NRT; rt++) {
            bf16x8s afrag = *reinterpret_cast<const bf16x8s*>(
                &Wlds[(size_t)((rt * 2 + 1) * 64 + l) * 8]);
            acc[rt] = __builtin_amdgcn_mfma_f32_16x16x32_bf16(afrag, bf1, acc[rt], 0, 0, 0);
        }
        xc0 = xn0;
        xc1 = xn1;
    }

    __syncthreads();   // done reading Wlds; reuse as transpose buffer
    // layout (ushort offsets): q = nl*72 + k*4 + h (rows 0..63), v = 4608 + nl*72 + v
    {
        int nl = w * 16 + lm;
#pragma unroll
        for (int rt = 0; rt < 4; rt++)
#pragma unroll
            for (int rr = 0; rr < 4; rr++) {
                int kq = hi * 4 + rr;
                Wlds[nl * 72 + kq * 4 + rt] = f2bf(acc[rt][rr] + bias[rt * 16 + kq]);
            }
#pragma unroll
        for (int rt = 5; rt < 9; rt++)
#pragma unroll
            for (int rr = 0; rr < 4; rr++) {
                int v = (rt - 5) * 16 + hi * 4 + rr;
                Wlds[4608 + nl * 72 + v] = f2bf(acc[rt][rr] + bias[80 + v]);
            }
    }
    __syncthreads();

    // ---- coalesced stores from LDS ----
#pragma unroll
    for (int m = 0; m < 2; m++) {
        int i = t + 256 * m;
        int row = i >> 3, seg = i & 7;
        uint4 u = *reinterpret_cast<const uint4*>(&Wlds[row * 72 + seg * 8]);
        *reinterpret_cast<uint4*>(&qbufT[((size_t)b * Nn + n0 + row) * 64 + seg * 8]) = u;
    }
#pragma unroll
    for (int m = 0; m < 2; m++) {
        int i = t + 256 * m;
        int row = i >> 3, seg = i & 7;
        uint4 u = *reinterpret_cast<const uint4*>(&Wlds[4608 + row * 72 + seg * 8]);
        *reinterpret_cast<uint4*>(&vbufT[((size_t)b * Nn + n0 + row) * 64 + seg * 8]) = u;
    }

    // ---- fused exp + lam contraction (kbuf eliminated) ----
    float ev[4];
#pragma unroll
    for (int rr = 0; rr < 4; rr++)
        ev[rr] = __expf(acc[4][rr] + bias[64 + hi * 4 + rr]);
    __syncthreads();   // q-region LDS reads (stores above) complete before overwrite
    float* eks = reinterpret_cast<float*>(Wlds);   // eks[k][n]: 16x64 fp32 (q region)
    {
        int nl = w * 16 + lm;
#pragma unroll
        for (int rr = 0; rr < 4; rr++)
            eks[(hi * 4 + rr) * 64 + nl] = ev[rr];
    }
    __syncthreads();
    {
        int v = t & 63, k0 = t >> 6;
        float a4[4] = {0.f, 0.f, 0.f, 0.f};
        for (int nl = 0; nl < 64; nl++) {
            float wv = bf2f(Wlds[4608 + nl * 72 + v]);
#pragma unroll
            for (int j2 = 0; j2 < 4; j2++)
                a4[j2] += eks[(k0 + 4 * j2) * 64 + nl] * wv;
        }
#pragma unroll
        for (int j2 = 0; j2 < 4; j2++)
            atomicAdd(&num[((size_t)b * Kk + k0 + 4 * j2) * Vv + v], a4[j2]);
        if (t < Kk) {
            float s = 0.f;
#pragma unroll
            for (int nl = 0; nl < 64; nl++) s += eks[t * 64 + nl];
            atomicAdd(&den[(size_t)b * Kk + t], s);
        }
    }
}

// ---------------- Kernel 3: fused output via MFMA (R22/R24 verified version) ----------------
#define TN 32
__global__ __launch_bounds__(256, 4) void fused_out_kernel(
    const ushort* __restrict__ qbufT, const ushort* __restrict__ vbufT,
    const ushort* __restrict__ cwf, const float* __restrict__ num,
    const float* __restrict__ den, const float* __restrict__ conv_b,
    float* __restrict__ out) {
    __shared__ ushort Af[12 * 64 * 8];      // 12288 B
    __shared__ ushort Sf[4][12 * 32 * 8];   // 24576 B
    __shared__ ushort Qf[4][2 * 64 * 8];    // [h][(nt*64+l)*8+j]; 8192 B

    int b = blockIdx.y;
    int n0 = blockIdx.x * TN;
    int t = threadIdx.x;
    int l = t & 63;

    // ---- issue all global loads first ----
    uint4 vld0 = {0, 0, 0, 0}, vld1 = {0, 0, 0, 0};
    {
        int c = t >> 3, vg = t & 7;
        int n = n0 - 11 + c;
        if (n >= 0 && n < Nn)
            vld0 = *reinterpret_cast<const uint4*>(&vbufT[((size_t)b * Nn + n) * 64 + vg * 8]);
        int i2 = t + 256;
        if (i2 < 432) {
            int c2 = i2 >> 3, vg2 = i2 & 7;
            int n2 = n0 - 11 + c2;
            if (n2 >= 0 && n2 < Nn)
                vld1 = *reinterpret_cast<const uint4*>(&vbufT[((size_t)b * Nn + n2) * 64 + vg2 * 8]);
        }
    }
    uint2 qld0, qld1;
    {
        int i = t;          // k = i>>5, nl = i&31
        qld0 = *reinterpret_cast<const uint2*>(
            &qbufT[((size_t)b * Nn + n0 + (i & 31)) * 64 + (i >> 5) * 4]);
        int i2 = t + 256;
        qld1 = *reinterpret_cast<const uint2*>(
            &qbufT[((size_t)b * Nn + n0 + (i2 & 31)) * 64 + (i2 >> 5) * 4]);
    }
    uint4 cwld0 = *reinterpret_cast<const uint4*>(&cwf[(0 * 64 + l) * 8]);
    uint4 cwld1 = *reinterpret_cast<const uint4*>(&cwf[(1 * 64 + l) * 8]);
    float4 lcl = *reinterpret_cast<const float4*>(&num[(size_t)b * Kk * Vv + t * 4]);
    float dk = den[(size_t)b * Kk + (t >> 4)];
    float cb = conv_b[t >> 4];

    // ---- zero-init fragments (Af slices 0..7 fully overwritten; zero only 8..11) ----
    uint4 z4 = {0, 0, 0, 0};
    reinterpret_cast<uint4*>(Af)[512 + t] = z4;
#pragma unroll
    for (int m = 0; m < 6; m++) reinterpret_cast<uint4*>(Sf)[t + 256 * m] = z4;
#pragma unroll
    for (int m = 0; m < 2; m++) reinterpret_cast<uint4*>(Qf)[t + 256 * m] = z4;
    __syncthreads();

    // ---- scatter fills ----
    // vv -> A cols 0..53
    {
        int c = t >> 3, vg = t & 7;
        int kk = c >> 5, hi = (c >> 3) & 3, j = c & 7;
        ushort* base = &Af[((kk * 4 + hi) * 64 + vg * 8) * 8 + j];
        uint va[4] = {vld0.x, vld0.y, vld0.z, vld0.w};
#pragma unroll
        for (int e = 0; e < 4; e++) {
            base[(2 * e + 0) * 8] = (ushort)(va[e] & 0xffff);
            base[(2 * e + 1) * 8] = (ushort)(va[e] >> 16);
        }
        int i2 = t + 256;
        if (i2 < 432) {
            int c2 = i2 >> 3, vg2 = i2 & 7;
            int kk2 = c2 >> 5, hi2 = (c2 >> 3) & 3, j2 = c2 & 7;
            ushort* base2 = &Af[((kk2 * 4 + hi2) * 64 + vg2 * 8) * 8 + j2];
            uint vb4[4] = {vld1.x, vld1.y, vld1.z, vld1.w};
#pragma unroll
            for (int e = 0; e < 4; e++) {
                base2[(2 * e + 0) * 8] = (ushort)(vb4[e] & 0xffff);
                base2[(2 * e + 1) * 8] = (ushort)(vb4[e] >> 16);
            }
        }
    }
    // lc = num/den + cb -> A cols 54..69
    {
        int k = t >> 4, v0 = (t & 15) * 4;
        int c = 54 + k;
        int kk = c >> 5, hi = (c >> 3) & 3, j = c & 7;
        ushort* base = &Af[((kk * 4 + hi) * 64 + v0) * 8 + j];
        float inv = 1.f / dk;
        base[0]  = f2bf(lcl.x * inv + cb);
        base[8]  = f2bf(lcl.y * inv + cb);
        base[16] = f2bf(lcl.z * inv + cb);
        base[24] = f2bf(lcl.w * inv + cb);
    }
    // q -> S rows 54..69 AND Qf B-fragments
    {
        int i = t;
        {
            int k = i >> 5, nl = i & 31, m = 54 + k;
            int kk = m >> 5, hi = (m >> 3) & 3, j = m & 7;
            int off = ((kk * 4 + hi) * 32 + nl) * 8 + j;
            Sf[0][off] = (ushort)(qld0.x & 0xffff);
            Sf[1][off] = (ushort)(qld0.x >> 16);
            Sf[2][off] = (ushort)(qld0.y & 0xffff);
            Sf[3][off] = (ushort)(qld0.y >> 16);
            int nt = nl >> 4, lmq = nl & 15;
            int qoff = (nt * 64 + (k >> 3) * 16 + lmq) * 8 + (k & 7);
            Qf[0][qoff] = (ushort)(qld0.x & 0xffff);
            Qf[1][qoff] = (ushort)(qld0.x >> 16);
            Qf[2][qoff] = (ushort)(qld0.y & 0xffff);
            Qf[3][qoff] = (ushort)(qld0.y >> 16);
        }
        int i2 = t + 256;
        {
            int k = i2 >> 5, nl = i2 & 31, m = 54 + k;
            int kk = m >> 5, hi = (m >> 3) & 3, j = m & 7;
            int off = ((kk * 4 + hi) * 32 + nl) * 8 + j;
            Sf[0][off] = (ushort)(qld1.x & 0xffff);
            Sf[1][off] = (ushort)(qld1.x >> 16);
            Sf[2][off] = (ushort)(qld1.y & 0xffff);
            Sf[3][off] = (ushort)(qld1.y >> 16);
            int nt = nl >> 4, lmq = nl & 15;
            int qoff = (nt * 64 + (k >> 3) * 16 + lmq) * 8 + (k & 7);
            Qf[0][qoff] = (ushort)(qld1.x & 0xffff);
            Qf[1][qoff] = (ushort)(qld1.x >> 16);
            Qf[2][qoff] = (ushort)(qld1.y & 0xffff);
            Qf[3][qoff] = (ushort)(qld1.y >> 16);
        }
    }
    __syncthreads();

    // ---- G-MFMA: wave h computes G_h(23x32) = cw^T x Q_h, scatters into Sf band ----
    int h = t >> 6;
    int lm = l & 15, hif = l >> 4;
    {
        bf16x8s cwfr0 = __builtin_bit_cast(bf16x8s, cwld0);
        bf16x8s cwfr1 = __builtin_bit_cast(bf16x8s, cwld1);
        f32x4 gacc[2][2];
#pragma unroll
        for (int nt = 0; nt < 2; nt++) {
            bf16x8s qfr = *reinterpret_cast<const bf16x8s*>(&Qf[h][(nt * 64 + l) * 8]);
            gacc[0][nt] = __builtin_amdgcn_mfma_f32_16x16x32_bf16(
                cwfr0, qfr, (f32x4){0.f, 0.f, 0.f, 0.f}, 0, 0, 0);
            gacc[1][nt] = __builtin_amdgcn_mfma_f32_16x16x32_bf16(
                cwfr1, qfr, (f32x4){0.f, 0.f, 0.f, 0.f}, 0, 0, 0);
        }
#pragma unroll
        for (int mt = 0; mt < 2; mt++)
#pragma unroll
            for (int nt = 0; nt < 2; nt++)
#pragma unroll
                for (int rr = 0; rr < 4; rr++) {
                    int r = mt * 16 + hif * 4 + rr;
                    if (r < Rr) {
                        int nl2 = nt * 16 + lm;
                        int m = nl2 + r;
                        Sf[h][((m >> 3) * 32 + nl2) * 8 + (m & 7)] = f2bf(gacc[mt][nt][rr]);
                    }
                }
    }
    __syncthreads();

    // ---- main MFMA: wave = h ----
    f32x4 acc[4][2];
#pragma unroll
    for (int mt = 0; mt < 4; mt++)
#pragma unroll
        for (int nt = 0; nt < 2; nt++) acc[mt][nt] = (f32x4){0.f, 0.f, 0.f, 0.f};

#pragma unroll
    for (int kk = 0; kk < 3; kk++) {
        bf16x8s bfr[2];
#pragma unroll
        for (int nt = 0; nt < 2; nt++)
            bfr[nt] = *reinterpret_cast<const bf16x8s*>(
                &Sf[h][((kk * 4 + hif) * 32 + nt * 16 + lm) * 8]);
#pragma unroll
        for (int mt = 0; mt < 4; mt++) {
            bf16x8s afr = *reinterpret_cast<const bf16x8s*>(
                &Af[((kk * 4 + hif) * 64 + mt * 16 + lm) * 8]);
#pragma unroll
            for (int nt = 0; nt < 2; nt++)
                acc[mt][nt] = __builtin_amdgcn_mfma_f32_16x16x32_bf16(afr, bfr[nt], acc[mt][nt], 0, 0, 0);
        }
    }

    // ---- store: C layout col=lane&15 (n), row=(lane>>4)*4+reg (v) ----
    float* ob = out + ((size_t)b * 256 + h * 64) * Nn + n0;
#pragma unroll
    for (int mt = 0; mt < 4; mt++)
#pragma unroll
        for (int nt = 0; nt < 2; nt++)
#pragma unroll
            for (int rr = 0; rr < 4; rr++) {
                int v = mt * 16 + hif * 4 + rr;
                ob[(size_t)v * Nn + nt * 16 + lm] = acc[mt][nt][rr];
            }
}

extern "C" void kernel_launch(void* const* d_in, const int* in_sizes, int n_in,
                              void* d_out, int out_size, void* d_ws, size_t ws_size,
                              hipStream_t stream) {
    const float* x      = (const float*)d_in[0];
    const float* Wq     = (const float*)d_in[1];
    const float* qg     = (const float*)d_in[2];
    const float* qb     = (const float*)d_in[3];
    const float* qm     = (const float*)d_in[4];
    const float* qv     = (const float*)d_in[5];
    const float* Wk     = (const float*)d_in[6];
    const float* Wv     = (const float*)d_in[7];
    const float* vg     = (const float*)d_in[8];
    const float* vb     = (const float*)d_in[9];
    const float* vm     = (const float*)d_in[10];
    const float* vvar   = (const float*)d_in[11];
    const float* conv_w = (const float*)d_in[12];
    const float* conv_b = (const float*)d_in[13];
    float* out = (float*)d_out;

    float* wsf = (float*)d_ws;
    ushort* Wf16  = (ushort*)wsf;                       // 36864 u16 = 18432 f
    float*  bias  = wsf + 18432;                        // 256 f
    float*  num   = wsf + 18688;                        // 16384 f
    float*  den   = wsf + 35072;                        // 256 f
    ushort* cwf   = (ushort*)(wsf + 35328);             // 1024 u16 = 512 f
    ushort* qbufT = (ushort*)(wsf + 35840);             // 16*4096*64 u16 = 2097152 f
    ushort* vbufT = (ushort*)(wsf + 2132992);           // 16*4096*64 u16

    pack_kernel<<<Cc, 256, 0, stream>>>(Wq, qg, qb, qm, qv, Wk, Wv, vg, vb, vm, vvar,
                                        conv_w, Wf16, bias, cwf, num, den);
    proj_mfma_kernel<<<dim3(Nn / 64, Bn), 256, 0, stream>>>(x, Wf16, bias,
                                                            qbufT, vbufT, num, den);
    fused_out_kernel<<<dim3(Nn / TN, Bn), 256, 0, stream>>>(qbufT, vbufT, cwf, num, den,
                                                            conv_b, out);
}